// Round 14
// baseline (366.548 us; speedup 1.0000x reference)
//
#include <hip/hip_runtime.h>
#include <hip/hip_bf16.h>
#include <math.h>

// LambdaLayer: B=32, DIM=512, H=W=32 (N=1024), DIM_K=16, HEADS=4, DIM_V=128, R=15
#define BATCH 32
#define DIMC  512
#define HGT   32
#define WID   32
#define NPOS  1024
#define DK    16
#define NHEADS 4
#define DV    128
#define RR    15
#define NQ    64

typedef __attribute__((ext_vector_type(8))) short short8;
typedef __attribute__((ext_vector_type(4))) float f32x4;
typedef unsigned short ushort_t;
typedef unsigned int uint_t;

// ws layout in ushort units:
static constexpr size_t U_WB   = 0;                       // [256][512] bf16
static constexpr size_t U_BIAS = 131072;                  // [256] f32 (512 ushorts)
static constexpr size_t U_Q    = 131584;                  // [B][64][1024] bf16
static constexpr size_t U_KSM  = U_Q   + (size_t)BATCH * NQ * NPOS;   // [B][16][1024] bf16
static constexpr size_t U_V    = U_KSM + (size_t)BATCH * DK * NPOS;   // [B][128][1024] bf16
static constexpr size_t U_CL   = U_V   + (size_t)BATCH * DV * NPOS;   // [B][128][16] bf16 ([v][k])

static __device__ __forceinline__ uint_t f2bf(float f) {
    return (uint_t)__builtin_bit_cast(unsigned short, __float2bfloat16(f));
}
static __device__ __forceinline__ float bf2f(ushort_t u) {
    return __builtin_bit_cast(float, ((uint_t)u) << 16);
}

// ---------------------------------------------------------------------------
// K0: weight prep — fold BN scale into bf16 weight rows, build bias vector.
// ---------------------------------------------------------------------------
__global__ __launch_bounds__(256) void wprep_kernel(
    const float* __restrict__ wq, const float* __restrict__ wk,
    const float* __restrict__ wv,
    const float* __restrict__ qg, const float* __restrict__ qb,
    const float* __restrict__ vg, const float* __restrict__ vb,
    ushort_t* __restrict__ ws_u)
{
    const int r = blockIdx.x;
    const int t = threadIdx.x;
    const float bninv = 1.0f / sqrtf(1.0f + 1e-5f);

    const float* src = nullptr; float scale = 0.f, bias = 0.f;
    if (r < 64)       { src = wq + (size_t)r * 512;        scale = qg[r] * bninv;      bias = qb[r]; }
    else if (r < 80)  { src = wk + (size_t)(r - 64) * 512; scale = 1.f;                bias = 0.f; }
    else if (r < 208) { src = wv + (size_t)(r - 80) * 512; scale = vg[r - 80] * bninv; bias = vb[r - 80]; }

    #pragma unroll
    for (int i = 0; i < 2; i++) {
        int cc = t + i * 256;
        float v = src ? src[cc] * scale : 0.f;
        ws_u[U_WB + (size_t)r * 512 + cc] = (ushort_t)f2bf(v);
    }
    if (t == 0) ((float*)(ws_u + U_BIAS))[r] = bias;
}

// ---------------------------------------------------------------------------
// K1 v4 (kept): Out[256][128] per block, 8 waves 4Mx2N, double-buffered
// B-tile (1 barrier/chunk), W-fragment register prefetch.
// ---------------------------------------------------------------------------
#define BSTR 72   // row stride hw: 64 + 8 pad

__global__ __launch_bounds__(512, 2) void proj_mfma_kernel(
    const float* __restrict__ x, ushort_t* __restrict__ ws_u)
{
    __shared__ ushort_t B_l[2][128 * BSTR];   // 2 x 18432 B
    __shared__ float bias_l[256];

    const int t  = threadIdx.x;
    const int blk = (int)((blockIdx.x & 7) * 32 + (blockIdx.x >> 3));  // 256 bijective
    const int b  = blk >> 3;
    const int n0 = (blk & 7) * 128;
    const int lane = t & 63;
    const int w  = t >> 6;
    const int wm = w & 3;
    const int wn = w >> 2;
    const int r15 = lane & 15;
    const int sl  = lane >> 4;

    if (t < 256) bias_l[t] = ((const float*)(ws_u + U_BIAS))[t];

    const float* xb = x + (size_t)b * DIMC * NPOS + n0;
    const ushort_t* wb = ws_u + U_WB;

    float4 xr[2][2];
    auto issue = [&](int c) {
        #pragma unroll
        for (int rep = 0; rep < 2; rep++) {
            int j  = rep * 512 + t;
            int pr = j >> 5, ng = j & 31;
            int d  = c * 64 + 2 * pr;
            xr[rep][0] = *(const float4*)&xb[(size_t)d * NPOS + 4 * ng];
            xr[rep][1] = *(const float4*)&xb[(size_t)(d + 1) * NPOS + 4 * ng];
        }
    };
    auto commit = [&](int buf) {
        #pragma unroll
        for (int rep = 0; rep < 2; rep++) {
            int j  = rep * 512 + t;
            int pr = j >> 5, ng = j & 31;
            int g  = pr >> 2;
            #pragma unroll
            for (int i = 0; i < 4; i++) {
                int n = 4 * ng + i;
                uint_t dw = f2bf(xr[rep][0][i]) | (f2bf(xr[rep][1][i]) << 16);
                int off = ((g ^ ((n >> 3) & 7)) << 3) + ((2 * pr) & 7);
                *(uint_t*)&B_l[buf][n * BSTR + off] = dw;
            }
        }
    };

    short8 af_a[2][4], af_b[2][4];
    auto af_load = [&](int c, short8 (*af)[4]) {
        #pragma unroll
        for (int kk = 0; kk < 2; kk++)
            #pragma unroll
            for (int mt = 0; mt < 4; mt++) {
                int row = wm * 64 + mt * 16 + r15;
                af[kk][mt] = *(const short8*)&wb[(size_t)row * 512 + c * 64 + kk * 32 + sl * 8];
            }
    };

    f32x4 acc[4][4];
    #pragma unroll
    for (int mt = 0; mt < 4; mt++)
        #pragma unroll
        for (int nt = 0; nt < 4; nt++) acc[mt][nt] = f32x4{0.f, 0.f, 0.f, 0.f};

    issue(0);
    commit(0);
    af_load(0, af_a);
    __syncthreads();

    for (int c = 0; c < 8; c++) {
        if (c < 7) { issue(c + 1); af_load(c + 1, af_b); }
        const int buf = c & 1;
        #pragma unroll
        for (int kk = 0; kk < 2; kk++) {
            short8 b_f[4];
            #pragma unroll
            for (int nt = 0; nt < 4; nt++) {
                int col = wn * 64 + nt * 16 + r15;
                int g   = kk * 4 + sl;
                int hw  = (g ^ ((col >> 3) & 7)) << 3;
                b_f[nt] = *(const short8*)&B_l[buf][col * BSTR + hw];
            }
            #pragma unroll
            for (int mt = 0; mt < 4; mt++)
                #pragma unroll
                for (int nt = 0; nt < 4; nt++)
                    acc[mt][nt] = __builtin_amdgcn_mfma_f32_16x16x32_bf16(
                        af_a[kk][mt], b_f[nt], acc[mt][nt], 0, 0, 0);
        }
        if (c < 7) {
            commit(1 - buf);
            __syncthreads();
            #pragma unroll
            for (int kk = 0; kk < 2; kk++)
                #pragma unroll
                for (int mt = 0; mt < 4; mt++) af_a[kk][mt] = af_b[kk][mt];
        }
    }

    ushort_t* qp = ws_u + U_Q   + (size_t)b * NQ * NPOS;
    ushort_t* kp = ws_u + U_KSM + (size_t)b * DK * NPOS;
    ushort_t* vp = ws_u + U_V   + (size_t)b * DV * NPOS;

    #pragma unroll
    for (int mt = 0; mt < 4; mt++) {
        int row0 = wm * 64 + mt * 16;
        if (row0 >= 208) continue;
        if (row0 == 64) {
            #pragma unroll
            for (int nt = 0; nt < 4; nt++) {
                int col = n0 + wn * 64 + nt * 16 + r15;
                f32x4 v = acc[mt][nt];
                float m = fmaxf(fmaxf(v[0], v[1]), fmaxf(v[2], v[3]));
                m = fmaxf(m, __shfl_xor(m, 16));
                m = fmaxf(m, __shfl_xor(m, 32));
                float e[4];
                float s = 0.f;
                #pragma unroll
                for (int i = 0; i < 4; i++) { e[i] = __expf(v[i] - m); s += e[i]; }
                s += __shfl_xor(s, 16);
                s += __shfl_xor(s, 32);
                float r = 1.0f / s;
                #pragma unroll
                for (int i = 0; i < 4; i++) {
                    int krow = sl * 4 + i;
                    kp[(size_t)krow * NPOS + col] = (ushort_t)f2bf(e[i] * r);
                }
            }
        } else {
            bool isq = row0 < 64;
            #pragma unroll
            for (int nt = 0; nt < 4; nt++) {
                int col = n0 + wn * 64 + nt * 16 + r15;
                #pragma unroll
                for (int i = 0; i < 4; i++) {
                    int row = row0 + sl * 4 + i;
                    float val = acc[mt][nt][i] + bias_l[row];
                    if (isq) qp[(size_t)row * NPOS + col] = (ushort_t)f2bf(val);
                    else     vp[(size_t)(row - 80) * NPOS + col] = (ushort_t)f2bf(val);
                }
            }
        }
    }
}

// ---------------------------------------------------------------------------
// K2 v2 (kept): content_lambda, 256 one-wave blocks.
// ---------------------------------------------------------------------------
__global__ __launch_bounds__(64) void cl_kernel(ushort_t* __restrict__ ws_u)
{
    const int b = (int)(blockIdx.x >> 3);
    const int w = (int)(blockIdx.x & 7);
    const int lane = threadIdx.x;
    const int r15 = lane & 15;
    const int sl  = lane >> 4;

    const ushort_t* kb = ws_u + U_KSM + (size_t)b * DK * NPOS + (size_t)r15 * NPOS;
    const ushort_t* vb = ws_u + U_V   + (size_t)b * DV * NPOS + (size_t)(w * 16 + r15) * NPOS;

    f32x4 a0 = f32x4{0.f, 0.f, 0.f, 0.f};
    f32x4 a1 = f32x4{0.f, 0.f, 0.f, 0.f};
    for (int ch = 0; ch < 32; ch += 2) {
        short8 af0 = *(const short8*)&kb[ch * 32 + sl * 8];
        short8 bf0 = *(const short8*)&vb[ch * 32 + sl * 8];
        a0 = __builtin_amdgcn_mfma_f32_16x16x32_bf16(af0, bf0, a0, 0, 0, 0);
        short8 af1 = *(const short8*)&kb[(ch + 1) * 32 + sl * 8];
        short8 bf1 = *(const short8*)&vb[(ch + 1) * 32 + sl * 8];
        a1 = __builtin_amdgcn_mfma_f32_16x16x32_bf16(af1, bf1, a1, 0, 0, 0);
    }

    ushort_t* clp = ws_u + U_CL + (size_t)b * DV * 16 + (size_t)(w * 16 + r15) * 16;
    #pragma unroll
    for (int i = 0; i < 4; i++)
        clp[sl * 4 + i] = (ushort_t)f2bf(a0[i] + a1[i]);
}

// ---------------------------------------------------------------------------
// K3 v8: banded-GEMM out kernel, A-operand DIRECT FROM GLOBAL (no A_l, no
// a_issue/a_commit): every lane's 16B A-fragment is fully in-image or fully
// zero (slab cols 8-aligned). LDS = B + Qt + ebt = 38.9 KB -> 4 blocks/CU.
// T5 setprio around band MFMA cluster.
// ---------------------------------------------------------------------------
#define ROWHW 104

__global__ __launch_bounds__(512, 8) void out_kernel(
    const float* __restrict__ emb, const ushort_t* __restrict__ ws_u,
    float* __restrict__ out)
{
    __shared__ ushort_t B_l[128 * ROWHW];       // 26624 B
    __shared__ ushort_t Qt_l[128 * 16];         // 4096 B  [c][k]
    __shared__ ushort_t ebt_l[256 * 16];        // 8192 B  [dy*16+dx][k]

    const int t = threadIdx.x;
    const int bid = (int)((blockIdx.x & 7) * 128 + (blockIdx.x >> 3));
    const int b = bid >> 5;
    const int y = bid & 31;
    const int lane = t & 63;
    const int w = t >> 6;            // 0..7
    const int wm = (w & 1) * 64;     // M base
    const int wn = (w >> 1) * 32;    // N base
    const int r15 = lane & 15;
    const int sl  = lane >> 4;

    const ushort_t* Vb  = ws_u + U_V  + (size_t)b * DV * NPOS;
    const ushort_t* CLb = ws_u + U_CL + (size_t)b * DV * 16;

    const short8 z8 = {0, 0, 0, 0, 0, 0, 0, 0};

    // direct-global A fragment: (p, ch) -> af[4] (per mt)
    auto load_a = [&](int p, int ch, short8* af) {
        const int cA  = ch * 32 + sl * 8;       // 0..95 within pair slab
        const int dyl = (cA >= 48) ? 1 : 0;
        const int cin = cA - dyl * 48;
        const int img = cin - 8;                // image col start of this 16B
        const int yy  = y + 2 * p + dyl - 7;
        const bool band_ok = (yy >= 0) && (yy < HGT) && (img >= 0) && (img <= 24);
        const bool is_cont = (p == 7) && (dyl == 1);
        #pragma unroll
        for (int mt = 0; mt < 4; mt++) {
            int row = wm + mt * 16 + r15;
            short8 a = z8;
            if (is_cont) {
                if (cin < 16) a = *(const short8*)&CLb[row * 16 + cin];
            } else if (band_ok) {
                a = *(const short8*)&Vb[(size_t)row * NPOS + yy * 32 + img];
            }
            af[mt] = a;
        }
    };

    f32x4 qacc[2];
    auto qe_mfma = [&](int pn) {
        short8 qa = (sl < 2) ? *(const short8*)&Qt_l[(w * 16 + r15) * 16 + sl * 8] : z8;
        #pragma unroll
        for (int jt = 0; jt < 2; jt++) {
            short8 eb = (sl < 2)
                ? *(const short8*)&ebt_l[(pn * 32 + jt * 16 + r15) * 16 + sl * 8] : z8;
            qacc[jt] = __builtin_amdgcn_mfma_f32_16x16x32_bf16(
                qa, eb, f32x4{0.f, 0.f, 0.f, 0.f}, 0, 0, 0);
        }
    };
    auto qe_scatter = [&](int pn) {
        #pragma unroll
        for (int jt = 0; jt < 2; jt++) {
            if (pn == 7 && jt == 1) continue;
            if (r15 < 15) {
                #pragma unroll
                for (int i = 0; i < 4; i++) {
                    int c = w * 16 + sl * 4 + i;
                    B_l[c * ROWHW + jt * 48 + (c & 31) + r15 + 1] =
                        (ushort_t)f2bf(qacc[jt][i]);
                }
            }
        }
        if (pn == 7) {   // content chunk: B[c][48+k] = Qt[c][k]
            #pragma unroll
            for (int rep = 0; rep < 2; rep++) {
                int d = rep * 512 + t;        // 0..1023 dwords
                int c = d >> 3, kk = (d & 7) * 2;
                *(uint_t*)&B_l[c * ROWHW + 48 + kk] = *(const uint_t*)&Qt_l[c * 16 + kk];
            }
        }
    };

    // ---- prologue: zero B, stage Qt + ebt
    {
        int* b4 = (int*)B_l;
        for (int i = t; i < 6656; i += 512) b4[i] = 0;
    }
    {   // Qt[c][k] = Q[b][ (c>>5)*16 + k ][ y*32 + (c&31) ]
        int c = t >> 2;
        const ushort_t* qp = ws_u + U_Q + ((size_t)b * NQ + (c >> 5) * 16) * NPOS
                           + y * 32 + (c & 31);
        #pragma unroll
        for (int i = 0; i < 4; i++) {
            int k = (t & 3) * 4 + i;
            Qt_l[c * 16 + k] = qp[(size_t)k * NPOS];
        }
    }
    {   // ebt[r=(dy*16+dx)][k] = emb[k][dy][dx]; zero for dx==15 or r>=240
        #pragma unroll
        for (int i = 0; i < 8; i++) {
            int idx = t * 8 + i;
            int r = idx >> 4, k = idx & 15;
            float val = 0.f;
            if (r < 240 && (r & 15) < RR)
                val = emb[k * (RR * RR) + (r >> 4) * RR + (r & 15)];
            ebt_l[idx] = (ushort_t)f2bf(val);
        }
    }
    __syncthreads();
    qe_mfma(0);
    qe_scatter(0);
    __syncthreads();

    f32x4 acc[4][2];
    #pragma unroll
    for (int mt = 0; mt < 4; mt++)
        #pragma unroll
        for (int nt = 0; nt < 2; nt++) acc[mt][nt] = f32x4{0.f, 0.f, 0.f, 0.f};

    for (int p = 0; p < 8; p++) {
        short8 afr[3][4];
        const int nch = (p < 7) ? 3 : 2;
        #pragma unroll
        for (int ch = 0; ch < 3; ch++)
            if (ch < nch) load_a(p, ch, afr[ch]);

        __builtin_amdgcn_s_setprio(1);
        #pragma unroll
        for (int ch = 0; ch < 3; ch++) {
            if (ch >= nch) continue;
            short8 b_f[2];
            #pragma unroll
            for (int nt = 0; nt < 2; nt++)
                b_f[nt] = *(const short8*)&B_l[(wn + nt * 16 + r15) * ROWHW + ch * 32 + sl * 8];
            #pragma unroll
            for (int mt = 0; mt < 4; mt++)
                #pragma unroll
                for (int nt = 0; nt < 2; nt++)
                    acc[mt][nt] = __builtin_amdgcn_mfma_f32_16x16x32_bf16(
                        afr[ch][mt], b_f[nt], acc[mt][nt], 0, 0, 0);
        }
        __builtin_amdgcn_s_setprio(0);

        if (p == 7) break;
        qe_mfma(p + 1);
        __syncthreads();
        qe_scatter(p + 1);
        __syncthreads();
    }

    // ---- epilogue
    float* ob = out + (size_t)b * 512 * NPOS + (size_t)y * 32;
    #pragma unroll
    for (int mt = 0; mt < 4; mt++) {
        #pragma unroll
        for (int nt = 0; nt < 2; nt++) {
            int vrow = wm + mt * 16 + sl * 4;
            int cc   = wn + nt * 16 + r15;
            int hh   = cc >> 5, xx = cc & 31;
            #pragma unroll
            for (int i = 0; i < 4; i++)
                ob[(size_t)(hh * 128 + vrow + i) * NPOS + xx] = acc[mt][nt][i];
        }
    }
}

// ---------------------------------------------------------------------------
extern "C" void kernel_launch(void* const* d_in, const int* in_sizes, int n_in,
                              void* d_out, int out_size, void* d_ws, size_t ws_size,
                              hipStream_t stream)
{
    const float* x   = (const float*)d_in[0];
    const float* wq  = (const float*)d_in[1];
    const float* wk  = (const float*)d_in[2];
    const float* wv  = (const float*)d_in[3];
    const float* emb = (const float*)d_in[4];
    const float* qg  = (const float*)d_in[5];
    const float* qb  = (const float*)d_in[6];
    const float* vg  = (const float*)d_in[7];
    const float* vb  = (const float*)d_in[8];
    float* out = (float*)d_out;
    ushort_t* ws_u = (ushort_t*)d_ws;

    hipLaunchKernelGGL(wprep_kernel, dim3(256), dim3(256), 0, stream,
                       wq, wk, wv, qg, qb, vg, vb, ws_u);
    hipLaunchKernelGGL(proj_mfma_kernel, dim3(BATCH * 8), dim3(512), 0, stream,
                       x, ws_u);
    hipLaunchKernelGGL(cl_kernel, dim3(BATCH * 8), dim3(64), 0, stream, ws_u);
    hipLaunchKernelGGL(out_kernel, dim3(BATCH * 32), dim3(512), 0, stream,
                       emb, ws_u, out);
}

// Round 15
// 97.849 us; speedup vs baseline: 3.7461x; 3.7461x over previous
//
#include <hip/hip_runtime.h>
#include <hip/hip_bf16.h>
#include <math.h>

// LambdaLayer: B=32, DIM=512, H=W=32 (N=1024), DIM_K=16, HEADS=4, DIM_V=128, R=15
#define BATCH 32
#define DIMC  512
#define HGT   32
#define WID   32
#define NPOS  1024
#define DK    16
#define NHEADS 4
#define DV    128
#define RR    15
#define NQ    64

typedef __attribute__((ext_vector_type(8))) short short8;
typedef __attribute__((ext_vector_type(4))) float f32x4;
typedef unsigned short ushort_t;
typedef unsigned int uint_t;

// ws layout in ushort units:
static constexpr size_t U_WB   = 0;                       // [256][512] bf16
static constexpr size_t U_BIAS = 131072;                  // [256] f32 (512 ushorts)
static constexpr size_t U_Q    = 131584;                  // [B][64][1024] bf16
static constexpr size_t U_KSM  = U_Q   + (size_t)BATCH * NQ * NPOS;   // [B][16][1024] bf16
static constexpr size_t U_V    = U_KSM + (size_t)BATCH * DK * NPOS;   // [B][128][1024] bf16
static constexpr size_t U_CL   = U_V   + (size_t)BATCH * DV * NPOS;   // [B][128][16] bf16 ([v][k])

static __device__ __forceinline__ uint_t f2bf(float f) {
    return (uint_t)__builtin_bit_cast(unsigned short, __float2bfloat16(f));
}
static __device__ __forceinline__ float bf2f(ushort_t u) {
    return __builtin_bit_cast(float, ((uint_t)u) << 16);
}

// ---------------------------------------------------------------------------
// K0: weight prep — fold BN scale into bf16 weight rows, build bias vector.
// ---------------------------------------------------------------------------
__global__ __launch_bounds__(256) void wprep_kernel(
    const float* __restrict__ wq, const float* __restrict__ wk,
    const float* __restrict__ wv,
    const float* __restrict__ qg, const float* __restrict__ qb,
    const float* __restrict__ vg, const float* __restrict__ vb,
    ushort_t* __restrict__ ws_u)
{
    const int r = blockIdx.x;
    const int t = threadIdx.x;
    const float bninv = 1.0f / sqrtf(1.0f + 1e-5f);

    const float* src = nullptr; float scale = 0.f, bias = 0.f;
    if (r < 64)       { src = wq + (size_t)r * 512;        scale = qg[r] * bninv;      bias = qb[r]; }
    else if (r < 80)  { src = wk + (size_t)(r - 64) * 512; scale = 1.f;                bias = 0.f; }
    else if (r < 208) { src = wv + (size_t)(r - 80) * 512; scale = vg[r - 80] * bninv; bias = vb[r - 80]; }

    #pragma unroll
    for (int i = 0; i < 2; i++) {
        int cc = t + i * 256;
        float v = src ? src[cc] * scale : 0.f;
        ws_u[U_WB + (size_t)r * 512 + cc] = (ushort_t)f2bf(v);
    }
    if (t == 0) ((float*)(ws_u + U_BIAS))[r] = bias;
}

// ---------------------------------------------------------------------------
// K1 v5: Out[256][128] per block, 8 waves 4Mx2N, double-buffered B-tile,
// W-fragment register prefetch, and DEPTH-2 x prefetch (parity register
// sets: chunk c's loads issued at iteration c-2).
// ---------------------------------------------------------------------------
#define BSTR 72   // row stride hw: 64 + 8 pad

__global__ __launch_bounds__(512, 2) void proj_mfma_kernel(
    const float* __restrict__ x, ushort_t* __restrict__ ws_u)
{
    __shared__ ushort_t B_l[2][128 * BSTR];   // 2 x 18432 B
    __shared__ float bias_l[256];

    const int t  = threadIdx.x;
    const int blk = (int)((blockIdx.x & 7) * 32 + (blockIdx.x >> 3));  // 256 bijective
    const int b  = blk >> 3;
    const int n0 = (blk & 7) * 128;
    const int lane = t & 63;
    const int w  = t >> 6;
    const int wm = w & 3;
    const int wn = w >> 2;
    const int r15 = lane & 15;
    const int sl  = lane >> 4;

    if (t < 256) bias_l[t] = ((const float*)(ws_u + U_BIAS))[t];

    const float* xb = x + (size_t)b * DIMC * NPOS + n0;
    const ushort_t* wb = ws_u + U_WB;

    // per chunk: 1024 jobs = (pr 0..31 d-pairs) x (ng 0..31 n-groups of 4)
    float4 xra[2][2], xrb[2][2];   // parity sets: even chunks -> a, odd -> b
    auto issue = [&](int c, float4 (*xr)[2]) {
        #pragma unroll
        for (int rep = 0; rep < 2; rep++) {
            int j  = rep * 512 + t;
            int pr = j >> 5, ng = j & 31;
            int d  = c * 64 + 2 * pr;
            xr[rep][0] = *(const float4*)&xb[(size_t)d * NPOS + 4 * ng];
            xr[rep][1] = *(const float4*)&xb[(size_t)(d + 1) * NPOS + 4 * ng];
        }
    };
    auto commit = [&](int buf, float4 (*xr)[2]) {
        #pragma unroll
        for (int rep = 0; rep < 2; rep++) {
            int j  = rep * 512 + t;
            int pr = j >> 5, ng = j & 31;
            int g  = pr >> 2;
            #pragma unroll
            for (int i = 0; i < 4; i++) {
                int n = 4 * ng + i;
                uint_t dw = f2bf(xr[rep][0][i]) | (f2bf(xr[rep][1][i]) << 16);
                int off = ((g ^ ((n >> 3) & 7)) << 3) + ((2 * pr) & 7);
                *(uint_t*)&B_l[buf][n * BSTR + off] = dw;
            }
        }
    };

    short8 af_a[2][4], af_b[2][4];
    auto af_load = [&](int c, short8 (*af)[4]) {
        #pragma unroll
        for (int kk = 0; kk < 2; kk++)
            #pragma unroll
            for (int mt = 0; mt < 4; mt++) {
                int row = wm * 64 + mt * 16 + r15;
                af[kk][mt] = *(const short8*)&wb[(size_t)row * 512 + c * 64 + kk * 32 + sl * 8];
            }
    };

    f32x4 acc[4][4];
    #pragma unroll
    for (int mt = 0; mt < 4; mt++)
        #pragma unroll
        for (int nt = 0; nt < 4; nt++) acc[mt][nt] = f32x4{0.f, 0.f, 0.f, 0.f};

    issue(0, xra);
    issue(1, xrb);
    af_load(0, af_a);
    commit(0, xra);              // waits only on chunk-0 loads
    __syncthreads();

    for (int c = 0; c < 8; c++) {
        const int buf = c & 1;
        if (c < 6) issue(c + 2, (c & 1) ? xrb : xra);   // set freed by commit(c)
        if (c < 7) af_load(c + 1, af_b);
        #pragma unroll
        for (int kk = 0; kk < 2; kk++) {
            short8 b_f[4];
            #pragma unroll
            for (int nt = 0; nt < 4; nt++) {
                int col = wn * 64 + nt * 16 + r15;
                int g   = kk * 4 + sl;
                int hw  = (g ^ ((col >> 3) & 7)) << 3;
                b_f[nt] = *(const short8*)&B_l[buf][col * BSTR + hw];
            }
            #pragma unroll
            for (int mt = 0; mt < 4; mt++)
                #pragma unroll
                for (int nt = 0; nt < 4; nt++)
                    acc[mt][nt] = __builtin_amdgcn_mfma_f32_16x16x32_bf16(
                        af_a[kk][mt], b_f[nt], acc[mt][nt], 0, 0, 0);
        }
        if (c < 7) {
            commit(1 - buf, (c & 1) ? xra : xrb);       // chunk c+1's parity set
            __syncthreads();
            #pragma unroll
            for (int kk = 0; kk < 2; kk++)
                #pragma unroll
                for (int mt = 0; mt < 4; mt++) af_a[kk][mt] = af_b[kk][mt];
        }
    }

    ushort_t* qp = ws_u + U_Q   + (size_t)b * NQ * NPOS;
    ushort_t* kp = ws_u + U_KSM + (size_t)b * DK * NPOS;
    ushort_t* vp = ws_u + U_V   + (size_t)b * DV * NPOS;

    #pragma unroll
    for (int mt = 0; mt < 4; mt++) {
        int row0 = wm * 64 + mt * 16;
        if (row0 >= 208) continue;
        if (row0 == 64) {
            #pragma unroll
            for (int nt = 0; nt < 4; nt++) {
                int col = n0 + wn * 64 + nt * 16 + r15;
                f32x4 v = acc[mt][nt];
                float m = fmaxf(fmaxf(v[0], v[1]), fmaxf(v[2], v[3]));
                m = fmaxf(m, __shfl_xor(m, 16));
                m = fmaxf(m, __shfl_xor(m, 32));
                float e[4];
                float s = 0.f;
                #pragma unroll
                for (int i = 0; i < 4; i++) { e[i] = __expf(v[i] - m); s += e[i]; }
                s += __shfl_xor(s, 16);
                s += __shfl_xor(s, 32);
                float r = 1.0f / s;
                #pragma unroll
                for (int i = 0; i < 4; i++) {
                    int krow = sl * 4 + i;
                    kp[(size_t)krow * NPOS + col] = (ushort_t)f2bf(e[i] * r);
                }
            }
        } else {
            bool isq = row0 < 64;
            #pragma unroll
            for (int nt = 0; nt < 4; nt++) {
                int col = n0 + wn * 64 + nt * 16 + r15;
                #pragma unroll
                for (int i = 0; i < 4; i++) {
                    int row = row0 + sl * 4 + i;
                    float val = acc[mt][nt][i] + bias_l[row];
                    if (isq) qp[(size_t)row * NPOS + col] = (ushort_t)f2bf(val);
                    else     vp[(size_t)(row - 80) * NPOS + col] = (ushort_t)f2bf(val);
                }
            }
        }
    }
}

// ---------------------------------------------------------------------------
// K2 v2 (kept): content_lambda, 256 one-wave blocks.
// ---------------------------------------------------------------------------
__global__ __launch_bounds__(64) void cl_kernel(ushort_t* __restrict__ ws_u)
{
    const int b = (int)(blockIdx.x >> 3);
    const int w = (int)(blockIdx.x & 7);
    const int lane = threadIdx.x;
    const int r15 = lane & 15;
    const int sl  = lane >> 4;

    const ushort_t* kb = ws_u + U_KSM + (size_t)b * DK * NPOS + (size_t)r15 * NPOS;
    const ushort_t* vb = ws_u + U_V   + (size_t)b * DV * NPOS + (size_t)(w * 16 + r15) * NPOS;

    f32x4 a0 = f32x4{0.f, 0.f, 0.f, 0.f};
    f32x4 a1 = f32x4{0.f, 0.f, 0.f, 0.f};
    for (int ch = 0; ch < 32; ch += 2) {
        short8 af0 = *(const short8*)&kb[ch * 32 + sl * 8];
        short8 bf0 = *(const short8*)&vb[ch * 32 + sl * 8];
        a0 = __builtin_amdgcn_mfma_f32_16x16x32_bf16(af0, bf0, a0, 0, 0, 0);
        short8 af1 = *(const short8*)&kb[(ch + 1) * 32 + sl * 8];
        short8 bf1 = *(const short8*)&vb[(ch + 1) * 32 + sl * 8];
        a1 = __builtin_amdgcn_mfma_f32_16x16x32_bf16(af1, bf1, a1, 0, 0, 0);
    }

    ushort_t* clp = ws_u + U_CL + (size_t)b * DV * 16 + (size_t)(w * 16 + r15) * 16;
    #pragma unroll
    for (int i = 0; i < 4; i++)
        clp[sl * 4 + i] = (ushort_t)f2bf(a0[i] + a1[i]);
}

// ---------------------------------------------------------------------------
// K3: banded-GEMM out kernel — R5 kernel verbatim (verified 44.8-45.1 us).
// ---------------------------------------------------------------------------
#define ROWHW 104

__global__ __launch_bounds__(512, 4) void out_kernel(
    const float* __restrict__ emb, const ushort_t* __restrict__ ws_u,
    float* __restrict__ out)
{
    __shared__ ushort_t A_l[DV * ROWHW];        // 26624 B
    __shared__ ushort_t B_l[128 * ROWHW];       // 26624 B
    __shared__ ushort_t Qt_l[128 * 16];         // 4096 B  [c][k]
    __shared__ ushort_t ebt_l[256 * 16];        // 8192 B  [dy*16+dx][k]

    const int t = threadIdx.x;
    const int bid = (int)((blockIdx.x & 7) * 128 + (blockIdx.x >> 3));
    const int b = bid >> 5;
    const int y = bid & 31;
    const int lane = t & 63;
    const int w = t >> 6;            // 0..7
    const int wm = (w & 1) * 64;     // M base
    const int wn = (w >> 1) * 32;    // N base
    const int r15 = lane & 15;
    const int sl  = lane >> 4;

    const ushort_t* Vb  = ws_u + U_V  + (size_t)b * DV * NPOS;
    const ushort_t* CLb = ws_u + U_CL + (size_t)b * DV * 16;

    const short8 z8 = {0, 0, 0, 0, 0, 0, 0, 0};

    int4 ar[2];
    auto a_issue = [&](int p) {
        #pragma unroll
        for (int rep = 0; rep < 2; rep++) {
            int idx = rep * 512 + t;
            int v   = idx >> 3;
            int dyl = (idx >> 2) & 1;
            int j   = idx & 3;
            int4 val; val.x = 0; val.y = 0; val.z = 0; val.w = 0;
            if (p == 7 && dyl == 1) {
                if (j < 2) val = *(const int4*)&CLb[v * 16 + 8 * j];
            } else {
                int yy = y + 2 * p + dyl - 7;
                if (yy >= 0 && yy < HGT)
                    val = *(const int4*)&Vb[(size_t)v * NPOS + yy * 32 + 8 * j];
            }
            ar[rep] = val;
        }
    };
    auto a_commit = [&](int p) {
        #pragma unroll
        for (int rep = 0; rep < 2; rep++) {
            int idx = rep * 512 + t;
            int v   = idx >> 3;
            int dyl = (idx >> 2) & 1;
            int j   = idx & 3;
            if (p == 7 && dyl == 1) {
                if (j < 2) *(int4*)&A_l[v * ROWHW + 48 + 8 * j] = ar[rep];
            } else {
                *(int4*)&A_l[v * ROWHW + dyl * 48 + 8 + 8 * j] = ar[rep];
            }
        }
    };

    f32x4 qacc[2];
    auto qe_mfma = [&](int pn) {
        short8 qa = (sl < 2) ? *(const short8*)&Qt_l[(w * 16 + r15) * 16 + sl * 8] : z8;
        #pragma unroll
        for (int jt = 0; jt < 2; jt++) {
            short8 eb = (sl < 2)
                ? *(const short8*)&ebt_l[(pn * 32 + jt * 16 + r15) * 16 + sl * 8] : z8;
            qacc[jt] = __builtin_amdgcn_mfma_f32_16x16x32_bf16(
                qa, eb, f32x4{0.f, 0.f, 0.f, 0.f}, 0, 0, 0);
        }
    };
    auto qe_scatter = [&](int pn) {
        #pragma unroll
        for (int jt = 0; jt < 2; jt++) {
            if (pn == 7 && jt == 1) continue;
            if (r15 < 15) {
                #pragma unroll
                for (int i = 0; i < 4; i++) {
                    int c = w * 16 + sl * 4 + i;
                    B_l[c * ROWHW + jt * 48 + (c & 31) + r15 + 1] =
                        (ushort_t)f2bf(qacc[jt][i]);
                }
            }
        }
        if (pn == 7) {   // content chunk: B[c][48+k] = Qt[c][k]
            #pragma unroll
            for (int rep = 0; rep < 2; rep++) {
                int d = rep * 512 + t;        // 0..1023 dwords
                int c = d >> 3, kk = (d & 7) * 2;
                *(uint_t*)&B_l[c * ROWHW + 48 + kk] = *(const uint_t*)&Qt_l[c * 16 + kk];
            }
        }
    };

    // ---- prologue: zero A/B, stage Qt + ebt, issue pair-0
    {
        int* a4 = (int*)A_l; int* b4 = (int*)B_l;
        for (int i = t; i < 6656; i += 512) { a4[i] = 0; b4[i] = 0; }
    }
    {   // Qt[c][k] = Q[b][ (c>>5)*16 + k ][ y*32 + (c&31) ]
        int c = t >> 2;
        const ushort_t* qp = ws_u + U_Q + ((size_t)b * NQ + (c >> 5) * 16) * NPOS
                           + y * 32 + (c & 31);
        #pragma unroll
        for (int i = 0; i < 4; i++) {
            int k = (t & 3) * 4 + i;
            Qt_l[c * 16 + k] = qp[(size_t)k * NPOS];
        }
    }
    {   // ebt[r=(dy*16+dx)][k] = emb[k][dy][dx]; zero for dx==15 or r>=240
        #pragma unroll
        for (int i = 0; i < 8; i++) {
            int idx = t * 8 + i;
            int r = idx >> 4, k = idx & 15;
            float val = 0.f;
            if (r < 240 && (r & 15) < RR)
                val = emb[k * (RR * RR) + (r >> 4) * RR + (r & 15)];
            ebt_l[idx] = (ushort_t)f2bf(val);
        }
    }
    a_issue(0);
    __syncthreads();
    a_commit(0);
    qe_mfma(0);
    qe_scatter(0);
    __syncthreads();

    f32x4 acc[4][2];
    #pragma unroll
    for (int mt = 0; mt < 4; mt++)
        #pragma unroll
        for (int nt = 0; nt < 2; nt++) acc[mt][nt] = f32x4{0.f, 0.f, 0.f, 0.f};

    for (int p = 0; p < 8; p++) {
        if (p < 7) a_issue(p + 1);
        const int nch = (p < 7) ? 3 : 2;
        for (int ch = 0; ch < nch; ch++) {
            short8 a_f[4], b_f[2];
            #pragma unroll
            for (int mt = 0; mt < 4; mt++)
                a_f[mt] = *(const short8*)&A_l[(wm + mt * 16 + r15) * ROWHW + ch * 32 + sl * 8];
            #pragma unroll
            for (int nt = 0; nt < 2; nt++)
                b_f[nt] = *(const short8*)&B_l[(wn + nt * 16 + r15) * ROWHW + ch * 32 + sl * 8];
            #pragma unroll
            for (int mt = 0; mt < 4; mt++)
                #pragma unroll
                for (int nt = 0; nt < 2; nt++)
                    acc[mt][nt] = __builtin_amdgcn_mfma_f32_16x16x32_bf16(
                        a_f[mt], b_f[nt], acc[mt][nt], 0, 0, 0);
        }
        if (p < 7) qe_mfma(p + 1);
        if (p == 7) break;
        __syncthreads();
        a_commit(p + 1);
        qe_scatter(p + 1);
        __syncthreads();
    }

    // ---- epilogue
    float* ob = out + (size_t)b * 512 * NPOS + (size_t)y * 32;
    #pragma unroll
    for (int mt = 0; mt < 4; mt++) {
        #pragma unroll
        for (int nt = 0; nt < 2; nt++) {
            int vrow = wm + mt * 16 + sl * 4;
            int cc   = wn + nt * 16 + r15;
            int hh   = cc >> 5, xx = cc & 31;
            #pragma unroll
            for (int i = 0; i < 4; i++)
                ob[(size_t)(hh * 128 + vrow + i) * NPOS + xx] = acc[mt][nt][i];
        }
    }
}

// ---------------------------------------------------------------------------
extern "C" void kernel_launch(void* const* d_in, const int* in_sizes, int n_in,
                              void* d_out, int out_size, void* d_ws, size_t ws_size,
                              hipStream_t stream)
{
    const float* x   = (const float*)d_in[0];
    const float* wq  = (const float*)d_in[1];
    const float* wk  = (const float*)d_in[2];
    const float* wv  = (const float*)d_in[3];
    const float* emb = (const float*)d_in[4];
    const float* qg  = (const float*)d_in[5];
    const float* qb  = (const float*)d_in[6];
    const float* vg  = (const float*)d_in[7];
    const float* vb  = (const float*)d_in[8];
    float* out = (float*)d_out;
    ushort_t* ws_u = (ushort_t*)d_ws;

    hipLaunchKernelGGL(wprep_kernel, dim3(256), dim3(256), 0, stream,
                       wq, wk, wv, qg, qb, vg, vb, ws_u);
    hipLaunchKernelGGL(proj_mfma_kernel, dim3(BATCH * 8), dim3(512), 0, stream,
                       x, ws_u);
    hipLaunchKernelGGL(cl_kernel, dim3(BATCH * 8), dim3(64), 0, stream, ws_u);
    hipLaunchKernelGGL(out_kernel, dim3(BATCH * 32), dim3(512), 0, stream,
                       emb, ws_u, out);
}

// Round 17
// 77.147 us; speedup vs baseline: 4.7513x; 1.2683x over previous
//
#include <hip/hip_runtime.h>
#include <hip/hip_bf16.h>
#include <math.h>

// LambdaLayer: B=32, DIM=512, H=W=32 (N=1024), DIM_K=16, HEADS=4, DIM_V=128, R=15
#define BATCH 32
#define DIMC  512
#define HGT   32
#define WID   32
#define NPOS  1024
#define DK    16
#define NHEADS 4
#define DV    128
#define RR    15
#define NQ    64

typedef __attribute__((ext_vector_type(8))) short short8;
typedef __attribute__((ext_vector_type(4))) float f32x4;
typedef unsigned short ushort_t;
typedef unsigned int uint_t;

// ws layout in ushort units:
static constexpr size_t U_WB   = 0;                       // [256][512] bf16
static constexpr size_t U_BIAS = 131072;                  // [256] f32 (512 ushorts)
static constexpr size_t U_Q    = 131584;                  // [B][64][1024] bf16
static constexpr size_t U_KSM  = U_Q   + (size_t)BATCH * NQ * NPOS;   // [B][16][1024] bf16
static constexpr size_t U_V    = U_KSM + (size_t)BATCH * DK * NPOS;   // [B][128][1024] bf16
static constexpr size_t U_CL   = U_V   + (size_t)BATCH * DV * NPOS;   // [B][128][16] bf16 ([v][k])

static __device__ __forceinline__ uint_t f2bf(float f) {
    return (uint_t)__builtin_bit_cast(unsigned short, __float2bfloat16(f));
}
static __device__ __forceinline__ float bf2f(ushort_t u) {
    return __builtin_bit_cast(float, ((uint_t)u) << 16);
}

// ---------------------------------------------------------------------------
// K0: weight prep — fold BN scale into bf16 weight rows, build bias vector.
// ---------------------------------------------------------------------------
__global__ __launch_bounds__(256) void wprep_kernel(
    const float* __restrict__ wq, const float* __restrict__ wk,
    const float* __restrict__ wv,
    const float* __restrict__ qg, const float* __restrict__ qb,
    const float* __restrict__ vg, const float* __restrict__ vb,
    ushort_t* __restrict__ ws_u)
{
    const int r = blockIdx.x;
    const int t = threadIdx.x;
    const float bninv = 1.0f / sqrtf(1.0f + 1e-5f);

    const float* src = nullptr; float scale = 0.f, bias = 0.f;
    if (r < 64)       { src = wq + (size_t)r * 512;        scale = qg[r] * bninv;      bias = qb[r]; }
    else if (r < 80)  { src = wk + (size_t)(r - 64) * 512; scale = 1.f;                bias = 0.f; }
    else if (r < 208) { src = wv + (size_t)(r - 80) * 512; scale = vg[r - 80] * bninv; bias = vb[r - 80]; }

    #pragma unroll
    for (int i = 0; i < 2; i++) {
        int cc = t + i * 256;
        float v = src ? src[cc] * scale : 0.f;
        ws_u[U_WB + (size_t)r * 512 + cc] = (ushort_t)f2bf(v);
    }
    if (t == 0) ((float*)(ws_u + U_BIAS))[r] = bias;
}

// ---------------------------------------------------------------------------
// K1 v4 (R13-exact): Out[256][128] per block, 8 waves 4Mx2N, double-buffered
// B-tile (1 barrier/chunk), W-fragment register prefetch (depth 1).
// ---------------------------------------------------------------------------
#define BSTR 72   // row stride hw: 64 + 8 pad

__global__ __launch_bounds__(512, 2) void proj_mfma_kernel(
    const float* __restrict__ x, ushort_t* __restrict__ ws_u)
{
    __shared__ ushort_t B_l[2][128 * BSTR];   // 2 x 18432 B
    __shared__ float bias_l[256];

    const int t  = threadIdx.x;
    const int blk = (int)((blockIdx.x & 7) * 32 + (blockIdx.x >> 3));  // 256 bijective
    const int b  = blk >> 3;
    const int n0 = (blk & 7) * 128;
    const int lane = t & 63;
    const int w  = t >> 6;
    const int wm = w & 3;
    const int wn = w >> 2;
    const int r15 = lane & 15;
    const int sl  = lane >> 4;

    if (t < 256) bias_l[t] = ((const float*)(ws_u + U_BIAS))[t];

    const float* xb = x + (size_t)b * DIMC * NPOS + n0;
    const ushort_t* wb = ws_u + U_WB;

    float4 xr[2][2];
    auto issue = [&](int c) {
        #pragma unroll
        for (int rep = 0; rep < 2; rep++) {
            int j  = rep * 512 + t;
            int pr = j >> 5, ng = j & 31;
            int d  = c * 64 + 2 * pr;
            xr[rep][0] = *(const float4*)&xb[(size_t)d * NPOS + 4 * ng];
            xr[rep][1] = *(const float4*)&xb[(size_t)(d + 1) * NPOS + 4 * ng];
        }
    };
    auto commit = [&](int buf) {
        #pragma unroll
        for (int rep = 0; rep < 2; rep++) {
            int j  = rep * 512 + t;
            int pr = j >> 5, ng = j & 31;
            int g  = pr >> 2;
            #pragma unroll
            for (int i = 0; i < 4; i++) {
                int n = 4 * ng + i;
                uint_t dw = f2bf(xr[rep][0][i]) | (f2bf(xr[rep][1][i]) << 16);
                int off = ((g ^ ((n >> 3) & 7)) << 3) + ((2 * pr) & 7);
                *(uint_t*)&B_l[buf][n * BSTR + off] = dw;
            }
        }
    };

    short8 af_a[2][4], af_b[2][4];
    auto af_load = [&](int c, short8 (*af)[4]) {
        #pragma unroll
        for (int kk = 0; kk < 2; kk++)
            #pragma unroll
            for (int mt = 0; mt < 4; mt++) {
                int row = wm * 64 + mt * 16 + r15;
                af[kk][mt] = *(const short8*)&wb[(size_t)row * 512 + c * 64 + kk * 32 + sl * 8];
            }
    };

    f32x4 acc[4][4];
    #pragma unroll
    for (int mt = 0; mt < 4; mt++)
        #pragma unroll
        for (int nt = 0; nt < 4; nt++) acc[mt][nt] = f32x4{0.f, 0.f, 0.f, 0.f};

    issue(0);
    commit(0);
    af_load(0, af_a);
    __syncthreads();

    for (int c = 0; c < 8; c++) {
        if (c < 7) { issue(c + 1); af_load(c + 1, af_b); }
        const int buf = c & 1;
        #pragma unroll
        for (int kk = 0; kk < 2; kk++) {
            short8 b_f[4];
            #pragma unroll
            for (int nt = 0; nt < 4; nt++) {
                int col = wn * 64 + nt * 16 + r15;
                int g   = kk * 4 + sl;
                int hw  = (g ^ ((col >> 3) & 7)) << 3;
                b_f[nt] = *(const short8*)&B_l[buf][col * BSTR + hw];
            }
            #pragma unroll
            for (int mt = 0; mt < 4; mt++)
                #pragma unroll
                for (int nt = 0; nt < 4; nt++)
                    acc[mt][nt] = __builtin_amdgcn_mfma_f32_16x16x32_bf16(
                        af_a[kk][mt], b_f[nt], acc[mt][nt], 0, 0, 0);
        }
        if (c < 7) {
            commit(1 - buf);
            __syncthreads();
            #pragma unroll
            for (int kk = 0; kk < 2; kk++)
                #pragma unroll
                for (int mt = 0; mt < 4; mt++) af_a[kk][mt] = af_b[kk][mt];
        }
    }

    ushort_t* qp = ws_u + U_Q   + (size_t)b * NQ * NPOS;
    ushort_t* kp = ws_u + U_KSM + (size_t)b * DK * NPOS;
    ushort_t* vp = ws_u + U_V   + (size_t)b * DV * NPOS;

    #pragma unroll
    for (int mt = 0; mt < 4; mt++) {
        int row0 = wm * 64 + mt * 16;
        if (row0 >= 208) continue;
        if (row0 == 64) {
            #pragma unroll
            for (int nt = 0; nt < 4; nt++) {
                int col = n0 + wn * 64 + nt * 16 + r15;
                f32x4 v = acc[mt][nt];
                float m = fmaxf(fmaxf(v[0], v[1]), fmaxf(v[2], v[3]));
                m = fmaxf(m, __shfl_xor(m, 16));
                m = fmaxf(m, __shfl_xor(m, 32));
                float e[4];
                float s = 0.f;
                #pragma unroll
                for (int i = 0; i < 4; i++) { e[i] = __expf(v[i] - m); s += e[i]; }
                s += __shfl_xor(s, 16);
                s += __shfl_xor(s, 32);
                float r = 1.0f / s;
                #pragma unroll
                for (int i = 0; i < 4; i++) {
                    int krow = sl * 4 + i;
                    kp[(size_t)krow * NPOS + col] = (ushort_t)f2bf(e[i] * r);
                }
            }
        } else {
            bool isq = row0 < 64;
            #pragma unroll
            for (int nt = 0; nt < 4; nt++) {
                int col = n0 + wn * 64 + nt * 16 + r15;
                #pragma unroll
                for (int i = 0; i < 4; i++) {
                    int row = row0 + sl * 4 + i;
                    float val = acc[mt][nt][i] + bias_l[row];
                    if (isq) qp[(size_t)row * NPOS + col] = (ushort_t)f2bf(val);
                    else     vp[(size_t)(row - 80) * NPOS + col] = (ushort_t)f2bf(val);
                }
            }
        }
    }
}

// ---------------------------------------------------------------------------
// K2 v2 (kept): content_lambda, 256 one-wave blocks.
// ---------------------------------------------------------------------------
__global__ __launch_bounds__(64) void cl_kernel(ushort_t* __restrict__ ws_u)
{
    const int b = (int)(blockIdx.x >> 3);
    const int w = (int)(blockIdx.x & 7);
    const int lane = threadIdx.x;
    const int r15 = lane & 15;
    const int sl  = lane >> 4;

    const ushort_t* kb = ws_u + U_KSM + (size_t)b * DK * NPOS + (size_t)r15 * NPOS;
    const ushort_t* vb = ws_u + U_V   + (size_t)b * DV * NPOS + (size_t)(w * 16 + r15) * NPOS;

    f32x4 a0 = f32x4{0.f, 0.f, 0.f, 0.f};
    f32x4 a1 = f32x4{0.f, 0.f, 0.f, 0.f};
    for (int ch = 0; ch < 32; ch += 2) {
        short8 af0 = *(const short8*)&kb[ch * 32 + sl * 8];
        short8 bf0 = *(const short8*)&vb[ch * 32 + sl * 8];
        a0 = __builtin_amdgcn_mfma_f32_16x16x32_bf16(af0, bf0, a0, 0, 0, 0);
        short8 af1 = *(const short8*)&kb[(ch + 1) * 32 + sl * 8];
        short8 bf1 = *(const short8*)&vb[(ch + 1) * 32 + sl * 8];
        a1 = __builtin_amdgcn_mfma_f32_16x16x32_bf16(af1, bf1, a1, 0, 0, 0);
    }

    ushort_t* clp = ws_u + U_CL + (size_t)b * DV * 16 + (size_t)(w * 16 + r15) * 16;
    #pragma unroll
    for (int i = 0; i < 4; i++)
        clp[sl * 4 + i] = (ushort_t)f2bf(a0[i] + a1[i]);
}

// ---------------------------------------------------------------------------
// K3 v9b: R5 banded-GEMM, TWO sequential y-tiles per block (y0, y0+16).
// Fix vs v9: tile-0's pair-7 content writes contaminate the zero-halo cells
// (A cols 48..55, B cols 48..63) that pairs 0..6 rely on — re-zero them
// before tile 1. All other cells are per-pair-rewritten or never touched.
// ---------------------------------------------------------------------------
#define ROWHW 104

__global__ __launch_bounds__(512, 4) void out_kernel(
    const float* __restrict__ emb, const ushort_t* __restrict__ ws_u,
    float* __restrict__ out)
{
    __shared__ ushort_t A_l[DV * ROWHW];        // 26624 B
    __shared__ ushort_t B_l[128 * ROWHW];       // 26624 B
    __shared__ ushort_t Qt_l[128 * 16];         // 4096 B  [c][k]
    __shared__ ushort_t ebt_l[256 * 16];        // 8192 B  [dy*16+dx][k]

    const int t = threadIdx.x;
    const int bid = (int)((blockIdx.x & 7) * 64 + (blockIdx.x >> 3));  // 512 bijective
    const int b  = bid >> 4;
    const int y0 = bid & 15;
    int y = y0;
    const int lane = t & 63;
    const int w = t >> 6;            // 0..7
    const int wm = (w & 1) * 64;     // M base
    const int wn = (w >> 1) * 32;    // N base
    const int r15 = lane & 15;
    const int sl  = lane >> 4;

    const ushort_t* Vb  = ws_u + U_V  + (size_t)b * DV * NPOS;
    const ushort_t* CLb = ws_u + U_CL + (size_t)b * DV * 16;

    const short8 z8 = {0, 0, 0, 0, 0, 0, 0, 0};

    int4 ar[2];
    auto a_issue = [&](int p) {
        #pragma unroll
        for (int rep = 0; rep < 2; rep++) {
            int idx = rep * 512 + t;
            int v   = idx >> 3;
            int dyl = (idx >> 2) & 1;
            int j   = idx & 3;
            int4 val; val.x = 0; val.y = 0; val.z = 0; val.w = 0;
            if (p == 7 && dyl == 1) {
                if (j < 2) val = *(const int4*)&CLb[v * 16 + 8 * j];
            } else {
                int yy = y + 2 * p + dyl - 7;
                if (yy >= 0 && yy < HGT)
                    val = *(const int4*)&Vb[(size_t)v * NPOS + yy * 32 + 8 * j];
            }
            ar[rep] = val;
        }
    };
    auto a_commit = [&](int p) {
        #pragma unroll
        for (int rep = 0; rep < 2; rep++) {
            int idx = rep * 512 + t;
            int v   = idx >> 3;
            int dyl = (idx >> 2) & 1;
            int j   = idx & 3;
            if (p == 7 && dyl == 1) {
                if (j < 2) *(int4*)&A_l[v * ROWHW + 48 + 8 * j] = ar[rep];
            } else {
                *(int4*)&A_l[v * ROWHW + dyl * 48 + 8 + 8 * j] = ar[rep];
            }
        }
    };

    f32x4 qacc[2];
    auto qe_mfma = [&](int pn) {
        short8 qa = (sl < 2) ? *(const short8*)&Qt_l[(w * 16 + r15) * 16 + sl * 8] : z8;
        #pragma unroll
        for (int jt = 0; jt < 2; jt++) {
            short8 eb = (sl < 2)
                ? *(const short8*)&ebt_l[(pn * 32 + jt * 16 + r15) * 16 + sl * 8] : z8;
            qacc[jt] = __builtin_amdgcn_mfma_f32_16x16x32_bf16(
                qa, eb, f32x4{0.f, 0.f, 0.f, 0.f}, 0, 0, 0);
        }
    };
    auto qe_scatter = [&](int pn) {
        #pragma unroll
        for (int jt = 0; jt < 2; jt++) {
            if (pn == 7 && jt == 1) continue;
            if (r15 < 15) {
                #pragma unroll
                for (int i = 0; i < 4; i++) {
                    int c = w * 16 + sl * 4 + i;
                    B_l[c * ROWHW + jt * 48 + (c & 31) + r15 + 1] =
                        (ushort_t)f2bf(qacc[jt][i]);
                }
            }
        }
        if (pn == 7) {   // content chunk: B[c][48+k] = Qt[c][k]
            #pragma unroll
            for (int rep = 0; rep < 2; rep++) {
                int d = rep * 512 + t;        // 0..1023 dwords
                int c = d >> 3, kk = (d & 7) * 2;
                *(uint_t*)&B_l[c * ROWHW + 48 + kk] = *(const uint_t*)&Qt_l[c * 16 + kk];
            }
        }
    };
    auto qt_stage = [&]() {
        int c = t >> 2;
        const ushort_t* qp = ws_u + U_Q + ((size_t)b * NQ + (c >> 5) * 16) * NPOS
                           + y * 32 + (c & 31);
        #pragma unroll
        for (int i = 0; i < 4; i++) {
            int k = (t & 3) * 4 + i;
            Qt_l[c * 16 + k] = qp[(size_t)k * NPOS];
        }
    };

    // ---- one-time prologue: zero A/B, stage ebt
    {
        int* a4 = (int*)A_l; int* b4 = (int*)B_l;
        for (int i = t; i < 6656; i += 512) { a4[i] = 0; b4[i] = 0; }
    }
    {   // ebt[r=(dy*16+dx)][k] = emb[k][dy][dx]; zero for dx==15 or r>=240
        #pragma unroll
        for (int i = 0; i < 8; i++) {
            int idx = t * 8 + i;
            int r = idx >> 4, k = idx & 15;
            float val = 0.f;
            if (r < 240 && (r & 15) < RR)
                val = emb[k * (RR * RR) + (r >> 4) * RR + (r & 15)];
            ebt_l[idx] = (ushort_t)f2bf(val);
        }
    }

    for (int ti = 0; ti < 2; ti++) {
        y = y0 + 16 * ti;
        if (ti) {
            __syncthreads();          // tile-0 reads of A_l/B_l/Qt_l done
            // re-zero cells contaminated by tile-0's pair-7 content writes:
            // A[v][48..55] (1 dword/thread), B[c][48..63] (2 dwords/thread)
            {
                int v = t >> 2;
                *(uint_t*)&A_l[v * ROWHW + 48 + (t & 3) * 2] = 0;
                #pragma unroll
                for (int rep = 0; rep < 2; rep++) {
                    int d = rep * 512 + t;
                    int c = d >> 3;
                    *(uint_t*)&B_l[c * ROWHW + 48 + (d & 7) * 2] = 0;
                }
            }
        }
        qt_stage();
        a_issue(0);
        __syncthreads();              // zeros / Qt visible
        a_commit(0);
        qe_mfma(0);
        qe_scatter(0);
        __syncthreads();

        f32x4 acc[4][2];
        #pragma unroll
        for (int mt = 0; mt < 4; mt++)
            #pragma unroll
            for (int nt = 0; nt < 2; nt++) acc[mt][nt] = f32x4{0.f, 0.f, 0.f, 0.f};

        for (int p = 0; p < 8; p++) {
            if (p < 7) a_issue(p + 1);
            const int nch = (p < 7) ? 3 : 2;
            for (int ch = 0; ch < nch; ch++) {
                short8 a_f[4], b_f[2];
                #pragma unroll
                for (int mt = 0; mt < 4; mt++)
                    a_f[mt] = *(const short8*)&A_l[(wm + mt * 16 + r15) * ROWHW + ch * 32 + sl * 8];
                #pragma unroll
                for (int nt = 0; nt < 2; nt++)
                    b_f[nt] = *(const short8*)&B_l[(wn + nt * 16 + r15) * ROWHW + ch * 32 + sl * 8];
                #pragma unroll
                for (int mt = 0; mt < 4; mt++)
                    #pragma unroll
                    for (int nt = 0; nt < 2; nt++)
                        acc[mt][nt] = __builtin_amdgcn_mfma_f32_16x16x32_bf16(
                            a_f[mt], b_f[nt], acc[mt][nt], 0, 0, 0);
            }
            if (p < 7) qe_mfma(p + 1);
            if (p == 7) break;
            __syncthreads();
            a_commit(p + 1);
            qe_scatter(p + 1);
            __syncthreads();
        }

        // ---- epilogue for this tile
        float* ob = out + (size_t)b * 512 * NPOS + (size_t)y * 32;
        #pragma unroll
        for (int mt = 0; mt < 4; mt++) {
            #pragma unroll
            for (int nt = 0; nt < 2; nt++) {
                int vrow = wm + mt * 16 + sl * 4;
                int cc   = wn + nt * 16 + r15;
                int hh   = cc >> 5, xx = cc & 31;
                #pragma unroll
                for (int i = 0; i < 4; i++)
                    ob[(size_t)(hh * 128 + vrow + i) * NPOS + xx] = acc[mt][nt][i];
            }
        }
    }
}

// ---------------------------------------------------------------------------
extern "C" void kernel_launch(void* const* d_in, const int* in_sizes, int n_in,
                              void* d_out, int out_size, void* d_ws, size_t ws_size,
                              hipStream_t stream)
{
    const float* x   = (const float*)d_in[0];
    const float* wq  = (const float*)d_in[1];
    const float* wk  = (const float*)d_in[2];
    const float* wv  = (const float*)d_in[3];
    const float* emb = (const float*)d_in[4];
    const float* qg  = (const float*)d_in[5];
    const float* qb  = (const float*)d_in[6];
    const float* vg  = (const float*)d_in[7];
    const float* vb  = (const float*)d_in[8];
    float* out = (float*)d_out;
    ushort_t* ws_u = (ushort_t*)d_ws;

    hipLaunchKernelGGL(wprep_kernel, dim3(256), dim3(256), 0, stream,
                       wq, wk, wv, qg, qb, vg, vb, ws_u);
    hipLaunchKernelGGL(proj_mfma_kernel, dim3(BATCH * 8), dim3(512), 0, stream,
                       x, ws_u);
    hipLaunchKernelGGL(cl_kernel, dim3(BATCH * 8), dim3(64), 0, stream, ws_u);
    hipLaunchKernelGGL(out_kernel, dim3(BATCH * 16), dim3(512), 0, stream,
                       emb, ws_u, out);
}

// Round 18
// 76.789 us; speedup vs baseline: 4.7735x; 1.0047x over previous
//
#include <hip/hip_runtime.h>
#include <hip/hip_bf16.h>
#include <math.h>

// LambdaLayer: B=32, DIM=512, H=W=32 (N=1024), DIM_K=16, HEADS=4, DIM_V=128, R=15
#define BATCH 32
#define DIMC  512
#define HGT   32
#define WID   32
#define NPOS  1024
#define DK    16
#define NHEADS 4
#define DV    128
#define RR    15
#define NQ    64

typedef __attribute__((ext_vector_type(8))) short short8;
typedef __attribute__((ext_vector_type(4))) float f32x4;
typedef unsigned short ushort_t;
typedef unsigned int uint_t;

// ws layout in ushort units:
static constexpr size_t U_WB   = 0;                       // [256][512] bf16
static constexpr size_t U_BIAS = 131072;                  // [256] f32 (512 ushorts)
static constexpr size_t U_Q    = 131584;                  // [B][64][1024] bf16
static constexpr size_t U_KSM  = U_Q   + (size_t)BATCH * NQ * NPOS;   // [B][16][1024] bf16
static constexpr size_t U_V    = U_KSM + (size_t)BATCH * DK * NPOS;   // [B][128][1024] bf16
static constexpr size_t U_CL   = U_V   + (size_t)BATCH * DV * NPOS;   // [B][128][16] bf16 ([v][k])

static __device__ __forceinline__ uint_t f2bf(float f) {
    return (uint_t)__builtin_bit_cast(unsigned short, __float2bfloat16(f));
}
static __device__ __forceinline__ float bf2f(ushort_t u) {
    return __builtin_bit_cast(float, ((uint_t)u) << 16);
}

// ---------------------------------------------------------------------------
// K0: weight prep — fold BN scale into bf16 weight rows, build bias vector.
// ---------------------------------------------------------------------------
__global__ __launch_bounds__(256) void wprep_kernel(
    const float* __restrict__ wq, const float* __restrict__ wk,
    const float* __restrict__ wv,
    const float* __restrict__ qg, const float* __restrict__ qb,
    const float* __restrict__ vg, const float* __restrict__ vb,
    ushort_t* __restrict__ ws_u)
{
    const int r = blockIdx.x;
    const int t = threadIdx.x;
    const float bninv = 1.0f / sqrtf(1.0f + 1e-5f);

    const float* src = nullptr; float scale = 0.f, bias = 0.f;
    if (r < 64)       { src = wq + (size_t)r * 512;        scale = qg[r] * bninv;      bias = qb[r]; }
    else if (r < 80)  { src = wk + (size_t)(r - 64) * 512; scale = 1.f;                bias = 0.f; }
    else if (r < 208) { src = wv + (size_t)(r - 80) * 512; scale = vg[r - 80] * bninv; bias = vb[r - 80]; }

    #pragma unroll
    for (int i = 0; i < 2; i++) {
        int cc = t + i * 256;
        float v = src ? src[cc] * scale : 0.f;
        ws_u[U_WB + (size_t)r * 512 + cc] = (ushort_t)f2bf(v);
    }
    if (t == 0) ((float*)(ws_u + U_BIAS))[r] = bias;
}

// ---------------------------------------------------------------------------
// K1 v6: Out[256][64] per block, 256 thr = 4 waves each 64 rows x 64 cols
// (32 MFMA/wave/interval, same as v4), grid = B x 16 = 512 blocks -> 2
// blocks/CU co-residency (barrier drains overlap across blocks). Dbuf
// B-tile (1 barrier/chunk) + W-fragment register prefetch, float4+XOR
// swizzle staging — all carried from v4.
// ---------------------------------------------------------------------------
#define BSTR 72   // row stride hw: 64 + 8 pad

__global__ __launch_bounds__(256, 3) void proj_mfma_kernel(
    const float* __restrict__ x, ushort_t* __restrict__ ws_u)
{
    __shared__ ushort_t B_l[2][64 * BSTR];    // 2 x 9216 B
    __shared__ float bias_l[256];

    const int t  = threadIdx.x;
    const int blk = (int)((blockIdx.x & 7) * 64 + (blockIdx.x >> 3));  // 512 bijective
    const int b  = blk >> 4;
    const int n0 = (blk & 15) * 64;
    const int lane = t & 63;
    const int w  = t >> 6;          // wave 0..3, M-tile rows w*64..w*64+63
    const int r15 = lane & 15;
    const int sl  = lane >> 4;

    bias_l[t] = ((const float*)(ws_u + U_BIAS))[t];

    const float* xb = x + (size_t)b * DIMC * NPOS + n0;
    const ushort_t* wb = ws_u + U_WB;

    // per chunk: 512 jobs = (pr 0..31 d-pairs) x (ng 0..15 col-groups of 4)
    float4 xr[2][2];
    auto issue = [&](int c) {
        #pragma unroll
        for (int rep = 0; rep < 2; rep++) {
            int j  = rep * 256 + t;
            int pr = j >> 4, ng = j & 15;
            int d  = c * 64 + 2 * pr;
            xr[rep][0] = *(const float4*)&xb[(size_t)d * NPOS + 4 * ng];
            xr[rep][1] = *(const float4*)&xb[(size_t)(d + 1) * NPOS + 4 * ng];
        }
    };
    auto commit = [&](int buf) {
        #pragma unroll
        for (int rep = 0; rep < 2; rep++) {
            int j  = rep * 256 + t;
            int pr = j >> 4, ng = j & 15;
            int g  = pr >> 2;
            #pragma unroll
            for (int i = 0; i < 4; i++) {
                int n = 4 * ng + i;
                uint_t dw = f2bf(xr[rep][0][i]) | (f2bf(xr[rep][1][i]) << 16);
                int off = ((g ^ ((n >> 3) & 7)) << 3) + ((2 * pr) & 7);
                *(uint_t*)&B_l[buf][n * BSTR + off] = dw;
            }
        }
    };

    short8 af_a[2][4], af_b[2][4];
    auto af_load = [&](int c, short8 (*af)[4]) {
        #pragma unroll
        for (int kk = 0; kk < 2; kk++)
            #pragma unroll
            for (int mt = 0; mt < 4; mt++) {
                int row = w * 64 + mt * 16 + r15;
                af[kk][mt] = *(const short8*)&wb[(size_t)row * 512 + c * 64 + kk * 32 + sl * 8];
            }
    };

    f32x4 acc[4][4];
    #pragma unroll
    for (int mt = 0; mt < 4; mt++)
        #pragma unroll
        for (int nt = 0; nt < 4; nt++) acc[mt][nt] = f32x4{0.f, 0.f, 0.f, 0.f};

    issue(0);
    commit(0);
    af_load(0, af_a);
    __syncthreads();

    for (int c = 0; c < 8; c++) {
        if (c < 7) { issue(c + 1); af_load(c + 1, af_b); }
        const int buf = c & 1;
        #pragma unroll
        for (int kk = 0; kk < 2; kk++) {
            short8 b_f[4];
            #pragma unroll
            for (int nt = 0; nt < 4; nt++) {
                int col = nt * 16 + r15;
                int g   = kk * 4 + sl;
                int hw  = (g ^ ((col >> 3) & 7)) << 3;
                b_f[nt] = *(const short8*)&B_l[buf][col * BSTR + hw];
            }
            #pragma unroll
            for (int mt = 0; mt < 4; mt++)
                #pragma unroll
                for (int nt = 0; nt < 4; nt++)
                    acc[mt][nt] = __builtin_amdgcn_mfma_f32_16x16x32_bf16(
                        af_a[kk][mt], b_f[nt], acc[mt][nt], 0, 0, 0);
        }
        if (c < 7) {
            commit(1 - buf);
            __syncthreads();
            #pragma unroll
            for (int kk = 0; kk < 2; kk++)
                #pragma unroll
                for (int mt = 0; mt < 4; mt++) af_a[kk][mt] = af_b[kk][mt];
        }
    }

    ushort_t* qp = ws_u + U_Q   + (size_t)b * NQ * NPOS;
    ushort_t* kp = ws_u + U_KSM + (size_t)b * DK * NPOS;
    ushort_t* vp = ws_u + U_V   + (size_t)b * DV * NPOS;

    #pragma unroll
    for (int mt = 0; mt < 4; mt++) {
        int row0 = w * 64 + mt * 16;
        if (row0 >= 208) continue;
        if (row0 == 64) {               // k tile -> column softmax over 16 rows
            #pragma unroll
            for (int nt = 0; nt < 4; nt++) {
                int col = n0 + nt * 16 + r15;
                f32x4 v = acc[mt][nt];
                float m = fmaxf(fmaxf(v[0], v[1]), fmaxf(v[2], v[3]));
                m = fmaxf(m, __shfl_xor(m, 16));
                m = fmaxf(m, __shfl_xor(m, 32));
                float e[4];
                float s = 0.f;
                #pragma unroll
                for (int i = 0; i < 4; i++) { e[i] = __expf(v[i] - m); s += e[i]; }
                s += __shfl_xor(s, 16);
                s += __shfl_xor(s, 32);
                float r = 1.0f / s;
                #pragma unroll
                for (int i = 0; i < 4; i++) {
                    int krow = sl * 4 + i;
                    kp[(size_t)krow * NPOS + col] = (ushort_t)f2bf(e[i] * r);
                }
            }
        } else {
            bool isq = row0 < 64;
            #pragma unroll
            for (int nt = 0; nt < 4; nt++) {
                int col = n0 + nt * 16 + r15;
                #pragma unroll
                for (int i = 0; i < 4; i++) {
                    int row = row0 + sl * 4 + i;
                    float val = acc[mt][nt][i] + bias_l[row];
                    if (isq) qp[(size_t)row * NPOS + col] = (ushort_t)f2bf(val);
                    else     vp[(size_t)(row - 80) * NPOS + col] = (ushort_t)f2bf(val);
                }
            }
        }
    }
}

// ---------------------------------------------------------------------------
// K2 v2 (kept): content_lambda, 256 one-wave blocks.
// ---------------------------------------------------------------------------
__global__ __launch_bounds__(64) void cl_kernel(ushort_t* __restrict__ ws_u)
{
    const int b = (int)(blockIdx.x >> 3);
    const int w = (int)(blockIdx.x & 7);
    const int lane = threadIdx.x;
    const int r15 = lane & 15;
    const int sl  = lane >> 4;

    const ushort_t* kb = ws_u + U_KSM + (size_t)b * DK * NPOS + (size_t)r15 * NPOS;
    const ushort_t* vb = ws_u + U_V   + (size_t)b * DV * NPOS + (size_t)(w * 16 + r15) * NPOS;

    f32x4 a0 = f32x4{0.f, 0.f, 0.f, 0.f};
    f32x4 a1 = f32x4{0.f, 0.f, 0.f, 0.f};
    for (int ch = 0; ch < 32; ch += 2) {
        short8 af0 = *(const short8*)&kb[ch * 32 + sl * 8];
        short8 bf0 = *(const short8*)&vb[ch * 32 + sl * 8];
        a0 = __builtin_amdgcn_mfma_f32_16x16x32_bf16(af0, bf0, a0, 0, 0, 0);
        short8 af1 = *(const short8*)&kb[(ch + 1) * 32 + sl * 8];
        short8 bf1 = *(const short8*)&vb[(ch + 1) * 32 + sl * 8];
        a1 = __builtin_amdgcn_mfma_f32_16x16x32_bf16(af1, bf1, a1, 0, 0, 0);
    }

    ushort_t* clp = ws_u + U_CL + (size_t)b * DV * 16 + (size_t)(w * 16 + r15) * 16;
    #pragma unroll
    for (int i = 0; i < 4; i++)
        clp[sl * 4 + i] = (ushort_t)f2bf(a0[i] + a1[i]);
}

// ---------------------------------------------------------------------------
// K3 v9b (R17-exact, 43.0 us): two sequential y-tiles per block with
// content-cell re-zero between tiles.
// ---------------------------------------------------------------------------
#define ROWHW 104

__global__ __launch_bounds__(512, 4) void out_kernel(
    const float* __restrict__ emb, const ushort_t* __restrict__ ws_u,
    float* __restrict__ out)
{
    __shared__ ushort_t A_l[DV * ROWHW];        // 26624 B
    __shared__ ushort_t B_l[128 * ROWHW];       // 26624 B
    __shared__ ushort_t Qt_l[128 * 16];         // 4096 B  [c][k]
    __shared__ ushort_t ebt_l[256 * 16];        // 8192 B  [dy*16+dx][k]

    const int t = threadIdx.x;
    const int bid = (int)((blockIdx.x & 7) * 64 + (blockIdx.x >> 3));  // 512 bijective
    const int b  = bid >> 4;
    const int y0 = bid & 15;
    int y = y0;
    const int lane = t & 63;
    const int w = t >> 6;            // 0..7
    const int wm = (w & 1) * 64;     // M base
    const int wn = (w >> 1) * 32;    // N base
    const int r15 = lane & 15;
    const int sl  = lane >> 4;

    const ushort_t* Vb  = ws_u + U_V  + (size_t)b * DV * NPOS;
    const ushort_t* CLb = ws_u + U_CL + (size_t)b * DV * 16;

    const short8 z8 = {0, 0, 0, 0, 0, 0, 0, 0};

    int4 ar[2];
    auto a_issue = [&](int p) {
        #pragma unroll
        for (int rep = 0; rep < 2; rep++) {
            int idx = rep * 512 + t;
            int v   = idx >> 3;
            int dyl = (idx >> 2) & 1;
            int j   = idx & 3;
            int4 val; val.x = 0; val.y = 0; val.z = 0; val.w = 0;
            if (p == 7 && dyl == 1) {
                if (j < 2) val = *(const int4*)&CLb[v * 16 + 8 * j];
            } else {
                int yy = y + 2 * p + dyl - 7;
                if (yy >= 0 && yy < HGT)
                    val = *(const int4*)&Vb[(size_t)v * NPOS + yy * 32 + 8 * j];
            }
            ar[rep] = val;
        }
    };
    auto a_commit = [&](int p) {
        #pragma unroll
        for (int rep = 0; rep < 2; rep++) {
            int idx = rep * 512 + t;
            int v   = idx >> 3;
            int dyl = (idx >> 2) & 1;
            int j   = idx & 3;
            if (p == 7 && dyl == 1) {
                if (j < 2) *(int4*)&A_l[v * ROWHW + 48 + 8 * j] = ar[rep];
            } else {
                *(int4*)&A_l[v * ROWHW + dyl * 48 + 8 + 8 * j] = ar[rep];
            }
        }
    };

    f32x4 qacc[2];
    auto qe_mfma = [&](int pn) {
        short8 qa = (sl < 2) ? *(const short8*)&Qt_l[(w * 16 + r15) * 16 + sl * 8] : z8;
        #pragma unroll
        for (int jt = 0; jt < 2; jt++) {
            short8 eb = (sl < 2)
                ? *(const short8*)&ebt_l[(pn * 32 + jt * 16 + r15) * 16 + sl * 8] : z8;
            qacc[jt] = __builtin_amdgcn_mfma_f32_16x16x32_bf16(
                qa, eb, f32x4{0.f, 0.f, 0.f, 0.f}, 0, 0, 0);
        }
    };
    auto qe_scatter = [&](int pn) {
        #pragma unroll
        for (int jt = 0; jt < 2; jt++) {
            if (pn == 7 && jt == 1) continue;
            if (r15 < 15) {
                #pragma unroll
                for (int i = 0; i < 4; i++) {
                    int c = w * 16 + sl * 4 + i;
                    B_l[c * ROWHW + jt * 48 + (c & 31) + r15 + 1] =
                        (ushort_t)f2bf(qacc[jt][i]);
                }
            }
        }
        if (pn == 7) {   // content chunk: B[c][48+k] = Qt[c][k]
            #pragma unroll
            for (int rep = 0; rep < 2; rep++) {
                int d = rep * 512 + t;        // 0..1023 dwords
                int c = d >> 3, kk = (d & 7) * 2;
                *(uint_t*)&B_l[c * ROWHW + 48 + kk] = *(const uint_t*)&Qt_l[c * 16 + kk];
            }
        }
    };
    auto qt_stage = [&]() {
        int c = t >> 2;
        const ushort_t* qp = ws_u + U_Q + ((size_t)b * NQ + (c >> 5) * 16) * NPOS
                           + y * 32 + (c & 31);
        #pragma unroll
        for (int i = 0; i < 4; i++) {
            int k = (t & 3) * 4 + i;
            Qt_l[c * 16 + k] = qp[(size_t)k * NPOS];
        }
    };

    // ---- one-time prologue: zero A/B, stage ebt
    {
        int* a4 = (int*)A_l; int* b4 = (int*)B_l;
        for (int i = t; i < 6656; i += 512) { a4[i] = 0; b4[i] = 0; }
    }
    {   // ebt[r=(dy*16+dx)][k] = emb[k][dy][dx]; zero for dx==15 or r>=240
        #pragma unroll
        for (int i = 0; i < 8; i++) {
            int idx = t * 8 + i;
            int r = idx >> 4, k = idx & 15;
            float val = 0.f;
            if (r < 240 && (r & 15) < RR)
                val = emb[k * (RR * RR) + (r >> 4) * RR + (r & 15)];
            ebt_l[idx] = (ushort_t)f2bf(val);
        }
    }

    for (int ti = 0; ti < 2; ti++) {
        y = y0 + 16 * ti;
        if (ti) {
            __syncthreads();          // tile-0 reads of A_l/B_l/Qt_l done
            // re-zero cells contaminated by tile-0's pair-7 content writes
            {
                int v = t >> 2;
                *(uint_t*)&A_l[v * ROWHW + 48 + (t & 3) * 2] = 0;
                #pragma unroll
                for (int rep = 0; rep < 2; rep++) {
                    int d = rep * 512 + t;
                    int c = d >> 3;
                    *(uint_t*)&B_l[c * ROWHW + 48 + (d & 7) * 2] = 0;
                }
            }
        }
        qt_stage();
        a_issue(0);
        __syncthreads();              // zeros / Qt visible
        a_commit(0);
        qe_mfma(0);
        qe_scatter(0);
        __syncthreads();

        f32x4 acc[4][2];
        #pragma unroll
        for (int mt = 0; mt < 4; mt++)
            #pragma unroll
            for (int nt = 0; nt < 2; nt++) acc[mt][nt] = f32x4{0.f, 0.f, 0.f, 0.f};

        for (int p = 0; p < 8; p++) {
            if (p < 7) a_issue(p + 1);
            const int nch = (p < 7) ? 3 : 2;
            for (int ch = 0; ch < nch; ch++) {
                short8 a_f[4], b_f[2];
                #pragma unroll
                for (int mt = 0; mt < 4; mt++)
                    a_f[mt] = *(const short8*)&A_l[(wm + mt * 16 + r15) * ROWHW + ch * 32 + sl * 8];
                #pragma unroll
                for (int nt = 0; nt < 2; nt++)
                    b_f[nt] = *(const short8*)&B_l[(wn + nt * 16 + r15) * ROWHW + ch * 32 + sl * 8];
                #pragma unroll
                for (int mt = 0; mt < 4; mt++)
                    #pragma unroll
                    for (int nt = 0; nt < 2; nt++)
                        acc[mt][nt] = __builtin_amdgcn_mfma_f32_16x16x32_bf16(
                            a_f[mt], b_f[nt], acc[mt][nt], 0, 0, 0);
            }
            if (p < 7) qe_mfma(p + 1);
            if (p == 7) break;
            __syncthreads();
            a_commit(p + 1);
            qe_scatter(p + 1);
            __syncthreads();
        }

        // ---- epilogue for this tile
        float* ob = out + (size_t)b * 512 * NPOS + (size_t)y * 32;
        #pragma unroll
        for (int mt = 0; mt < 4; mt++) {
            #pragma unroll
            for (int nt = 0; nt < 2; nt++) {
                int vrow = wm + mt * 16 + sl * 4;
                int cc   = wn + nt * 16 + r15;
                int hh   = cc >> 5, xx = cc & 31;
                #pragma unroll
                for (int i = 0; i < 4; i++)
                    ob[(size_t)(hh * 128 + vrow + i) * NPOS + xx] = acc[mt][nt][i];
            }
        }
    }
}

// ---------------------------------------------------------------------------
extern "C" void kernel_launch(void* const* d_in, const int* in_sizes, int n_in,
                              void* d_out, int out_size, void* d_ws, size_t ws_size,
                              hipStream_t stream)
{
    const float* x   = (const float*)d_in[0];
    const float* wq  = (const float*)d_in[1];
    const float* wk  = (const float*)d_in[2];
    const float* wv  = (const float*)d_in[3];
    const float* emb = (const float*)d_in[4];
    const float* qg  = (const float*)d_in[5];
    const float* qb  = (const float*)d_in[6];
    const float* vg  = (const float*)d_in[7];
    const float* vb  = (const float*)d_in[8];
    float* out = (float*)d_out;
    ushort_t* ws_u = (ushort_t*)d_ws;

    hipLaunchKernelGGL(wprep_kernel, dim3(256), dim3(256), 0, stream,
                       wq, wk, wv, qg, qb, vg, vb, ws_u);
    hipLaunchKernelGGL(proj_mfma_kernel, dim3(BATCH * 16), dim3(256), 0, stream,
                       x, ws_u);
    hipLaunchKernelGGL(cl_kernel, dim3(BATCH * 8), dim3(64), 0, stream, ws_u);
    hipLaunchKernelGGL(out_kernel, dim3(BATCH * 16), dim3(512), 0, stream,
                       emb, ws_u, out);
}